// Round 6
// baseline (459.457 us; speedup 1.0000x reference)
//
#include <hip/hip_runtime.h>

#define S_LEN 2048
#define B_SZ 2048

// Pure-VALU DPP move (no LDS pipe).
template <int CTRL>
__device__ __forceinline__ float dppmov(float v) {
  int r = __builtin_amdgcn_update_dpp(0, __builtin_bit_cast(int, v), CTRL, 0xF,
                                      0xF, true);
  return __builtin_bit_cast(float, r);
}

// readlane: broadcast lane L's value to an SGPR (no memory counter).
__device__ __forceinline__ float rlane(float v, int l) {
  return __builtin_bit_cast(
      float, __builtin_amdgcn_readlane(__builtin_bit_cast(int, v), l));
}

// Decomposition: wave = 1 batch element; 16-lane row r = layer r; within a
// row G = j*4 + ty (j = hidden unit = quad, ty = gate 0=i 1=f 2=g 3=o).
// NEW in R6: 2-tick layer skew (layer l processes t = tau - 2l) with
// ping-pong LDS buffers. Publish h -> buf[tau&1] at tick bottom; read the
// OTHER buffer (written last tick) at tick TOP into HN, consumed next tick.
// The DS read is in flight for a full tick (~200+ cyc) instead of ~30.
// P = tau&1 (compile-time in the unrolled body). HC = hin consumed this
// tick, HN = hin loaded for next tick.
#define TICK(P, ST, XVX, XVY, TT, HC, HN)                                      \
  do {                                                                         \
    /* top: read buf[P^1] (published last tick), consumed NEXT tick */         \
    HN = slot4[((P) ^ 1) * 4 + rd_slot];                                       \
    /* unified 10-term pre-activation (x zero-weighted on rows>0,   */         \
    /* hin zero-weighted on row 0; kk pre-folded into all weights)  */         \
    float t0 = fmaf(wx0, (XVX), fmaf(wx1, (XVY), bias));                       \
    float t1 = fmaf(wiH[1], HC.y, wiH[0] * HC.x);                              \
    float t4 = fmaf(wiH[3], HC.w, wiH[2] * HC.z);                              \
    float t2 = fmaf(wh[1], hv[1], wh[0] * hv[0]);                              \
    float t3 = fmaf(wh[3], hv[3], wh[2] * hv[2]);                              \
    float a = ((t0 + t1) + t4) + (t2 + t3);                                    \
    float e = __builtin_amdgcn_exp2f(a);                                       \
    float r = __builtin_amdgcn_rcpf(1.0f + e);                                 \
    float g = fmaf(mm, r, dd);                                                 \
    float q = g * dppmov<0x4E>(g); /* i*g lands on ty0 lane */                 \
    float pig = dppmov<0x00>(q);                                               \
    float gf = dppmov<0x55>(g);                                                \
    float go = dppmov<0xFF>(g);                                                \
    c = fmaf(gf, c, pig);                                                      \
    float te = __builtin_amdgcn_exp2f(c * KT);                                 \
    float tr = __builtin_amdgcn_rcpf(1.0f + te);                               \
    float hh = go * fmaf(2.0f, tr, -1.0f);                                     \
    hv[0] = hh;                                                                \
    hv[1] = dppmov<0x124>(hh);                                                 \
    hv[2] = dppmov<0x128>(hh);                                                 \
    hv[3] = dppmov<0x12C>(hh);                                                 \
    /* publish own h to buf[P]; trash bin for non-ty0 lanes */                 \
    slotf[(P) ? wrB : wrA] = hh;                                               \
    __builtin_amdgcn_wave_barrier();                                           \
    if (ST) {                                                                  \
      float y = fmaf(                                                          \
          wo[0], hv[0],                                                        \
          fmaf(wo[1], hv[1], fmaf(wo[2], hv[2], fmaf(wo[3], hv[3], bo))));     \
      if (do_store) out[(TT)*B_SZ + bidx] = y;                                 \
    }                                                                          \
  } while (0)

// warm-up tick: TICK + zero the not-yet-live layers (first real tick of
// layer l is tau = 2l)
#define WTICK(P, TAU, XVX, XVY, HC, HN)                                        \
  do {                                                                         \
    TICK(P, false, XVX, XVY, 0, HC, HN);                                       \
    if (2 * row > (TAU)) {                                                     \
      c = 0;                                                                   \
      hv[0] = hv[1] = hv[2] = hv[3] = 0;                                       \
    }                                                                          \
  } while (0)

__global__ void __launch_bounds__(64, 2)
    lstm_kernel(const float *__restrict__ x, const float *__restrict__ Wih0,
                const float *__restrict__ Whh0, const float *__restrict__ bih0,
                const float *__restrict__ bhh0, const float *__restrict__ Wihr,
                const float *__restrict__ Whhr, const float *__restrict__ bihr,
                const float *__restrict__ bhhr, const float *__restrict__ Wout,
                const float *__restrict__ bout, float *__restrict__ out) {
  // 2 ping-pong buffers x 16 slots (layer x hidden) + 64-float trash bin
  __shared__ __align__(16) float slotf[112];
  float4 *slot4 = (float4 *)slotf;

  const int lane = threadIdx.x & 63;
  const int ty = lane & 3;             // gate type
  const int j = (lane >> 2) & 3;       // hidden unit (quad)
  const int row = lane >> 4;           // layer
  const int bidx = blockIdx.x;         // batch element (1 per wave)
  const int wrow = ty * 4 + j;         // PyTorch weight row = type*H + j
  const bool do_store = (lane == 48);  // layer 3, G==0
  const int wrA = (ty == 0) ? ((row << 2) | j) : (96 + (lane & 15));
  const int wrB = (ty == 0) ? (16 + ((row << 2) | j)) : (96 + (lane & 15));
  const int rd_slot = (row + 3) & 3;   // layer row-1's slot (row0: ignored)

  // zero-init LDS (both buffers + trash)
  slotf[lane] = 0.0f;
  if (lane < 48) slotf[64 + lane] = 0.0f;
  __builtin_amdgcn_wave_barrier();

  // ---- detect ROW_ROR direction (init-only, direction-proof) ----
  float pr = dppmov<0x124>((float)j);
  const int s = (((int)pr) - j) & 3;
  int rix[4] = {j, (j + s) & 3, (j + 2) & 3, (j + 3 * s) & 3};

  // per-lane activation constants: sigmoid for i,f,o; tanh for g
  const float L2E = 1.4426950408889634f;
  const float kk = (ty == 2) ? -2.0f * L2E : -L2E;
  const float mm = (ty == 2) ? 2.0f : 1.0f;
  const float dd = (ty == 2) ? -1.0f : 0.0f;
  const float KT = -2.8853900817779268f;  // -2*log2(e)

  // ---- weight rows: wx (x terms, row0 only), wiH (natural order, rows>0),
  //      wh (pre-rotated); all pre-scaled by kk ----
  float wx0, wx1, wiH[4], wh[4], bias;
  if (row == 0) {
    wx0 = kk * Wih0[wrow * 2 + 0];
    wx1 = kk * Wih0[wrow * 2 + 1];
    wiH[0] = wiH[1] = wiH[2] = wiH[3] = 0.0f;
#pragma unroll
    for (int k = 0; k < 4; ++k) wh[k] = kk * Whh0[wrow * 4 + rix[k]];
    bias = kk * (bih0[wrow] + bhh0[wrow]);
  } else {
    const int l = row - 1;
    wx0 = 0.0f;
    wx1 = 0.0f;
#pragma unroll
    for (int k = 0; k < 4; ++k) {
      wiH[k] = kk * Wihr[l * 64 + wrow * 4 + k];
      wh[k] = kk * Whhr[l * 64 + wrow * 4 + rix[k]];
    }
    bias = kk * (bihr[l * 16 + wrow] + bhhr[l * 16 + wrow]);
  }
  float wo[4];
#pragma unroll
  for (int k = 0; k < 4; ++k) wo[k] = Wout[rix[k]];
  const float bo = bout[0];

  // ---- recurrent state ----
  float hv[4] = {0, 0, 0, 0};  // own layer h (rotated order)
  float4 hinA = {0, 0, 0, 0};  // prev layer h (natural), ping
  float4 hinB = {0, 0, 0, 0};  //                         pong
  float c = 0.0f;

  const float2 *__restrict__ px = (const float2 *)x;  // [S*B] float2 (IN=2)

  // divergent x loader: lane (lane&7) fetches tick base+(lane&7); one
  // global_load_dwordx2 per 8 ticks (vmcnt domain, no lgkmcnt pollution).
  const int l8 = lane & 7;
  auto ldx = [&](int base) -> float2 {
    int t = base + l8;
    if (t > S_LEN - 1) t = S_LEN - 1;  // clamp: drain values never stored
    return px[t * B_SZ + bidx];
  };

  // ---- warm-up ticks 0..5 (skew-2 pipeline fill) ----
  {
    float2 xv = px[0 * B_SZ + bidx];
    WTICK(0, 0, xv.x, xv.y, hinA, hinB);
    xv = px[1 * B_SZ + bidx];
    WTICK(1, 1, xv.x, xv.y, hinB, hinA);
    xv = px[2 * B_SZ + bidx];
    WTICK(0, 2, xv.x, xv.y, hinA, hinB);
    xv = px[3 * B_SZ + bidx];
    WTICK(1, 3, xv.x, xv.y, hinB, hinA);
    xv = px[4 * B_SZ + bidx];
    WTICK(0, 4, xv.x, xv.y, hinA, hinB);
    xv = px[5 * B_SZ + bidx];
    WTICK(1, 5, xv.x, xv.y, hinB, hinA);
  }

  // ---- x double-buffer: 8..16 ticks ahead ----
  float2 xa = ldx(6);   // ticks 6..13
  float2 xb = ldx(14);  // ticks 14..21

  // ---- main loop: ticks 6..2053 (2048 = 256 x 8); tt = tau - 6 ----
  for (int it = 0; it < 256; ++it) {
    float2 xn = ldx(22 + it * 8);  // refill, consumed 16 ticks later
#pragma unroll
    for (int u = 0; u < 8; ++u) {
      const int tt = it * 8 + u;  // store timestep (layer 3's t)
      float xvx = rlane(xa.x, u);
      float xvy = rlane(xa.y, u);
      if ((u & 1) == 0) {
        TICK(0, true, xvx, xvy, tt, hinA, hinB);
      } else {
        TICK(1, true, xvx, xvy, tt, hinB, hinA);
      }
    }
    xa = xb;
    xb = xn;
  }
}

extern "C" void kernel_launch(void *const *d_in, const int *in_sizes, int n_in,
                              void *d_out, int out_size, void *d_ws,
                              size_t ws_size, hipStream_t stream) {
  (void)in_sizes;
  (void)n_in;
  (void)out_size;
  (void)d_ws;
  (void)ws_size;
  const float *x = (const float *)d_in[0];
  const float *Wih0 = (const float *)d_in[1];
  const float *Whh0 = (const float *)d_in[2];
  const float *bih0 = (const float *)d_in[3];
  const float *bhh0 = (const float *)d_in[4];
  const float *Wihr = (const float *)d_in[5];
  const float *Whhr = (const float *)d_in[6];
  const float *bihr = (const float *)d_in[7];
  const float *bhhr = (const float *)d_in[8];
  const float *Wout = (const float *)d_in[9];
  const float *bout = (const float *)d_in[10];
  lstm_kernel<<<dim3(B_SZ), dim3(64), 0, stream>>>(
      x, Wih0, Whh0, bih0, bhh0, Wihr, Whhr, bihr, bhhr, Wout, bout,
      (float *)d_out);
}